// Round 2
// baseline (1054.449 us; speedup 1.0000x reference)
//
#include <hip/hip_runtime.h>

constexpr int ROWS   = 128;
constexpr int T      = 30;
constexpr int W      = 5;
constexpr int NOUT   = T - W + 1;              // 26
constexpr int NPAIRS = ROWS * (ROWS + 1) / 2;  // 8256

__global__ __launch_bounds__(256) void ts_cov_kernel(const float* __restrict__ in,
                                                     float* __restrict__ out) {
    __shared__ float x[ROWS * T];  // 15360 B
    const int b   = blockIdx.x;
    const int tid = threadIdx.x;

    // Coalesced global -> LDS load of this batch's [128,30] tile
    const float* inb = in + (size_t)b * (ROWS * T);
    for (int k = tid; k < ROWS * T; k += 256) x[k] = inb[k];
    __syncthreads();

    // Per-row normalization (population std), one thread per row.
    // LDS addr = r*30 + t: stride 30 across lanes -> 2-way bank aliasing (free).
    if (tid < ROWS) {
        float s = 0.f;
        #pragma unroll
        for (int t = 0; t < T; ++t) s += x[tid * T + t];
        const float mean = s * (1.0f / T);
        float v = 0.f;
        #pragma unroll
        for (int t = 0; t < T; ++t) {
            const float c = x[tid * T + t] - mean;
            v += c * c;
        }
        const float inv_std = rsqrtf(v * (1.0f / T));
        #pragma unroll
        for (int t = 0; t < T; ++t) x[tid * T + t] = (x[tid * T + t] - mean) * inv_std;
    }
    __syncthreads();

    float* outb = out + (size_t)b * NPAIRS * NOUT;

    for (int p = tid; p < NPAIRS; p += 256) {
        // Invert p -> (i, j), upper-triangular row-major:
        // f(i) = i*ROWS - i*(i-1)/2 is the first pair index of row i.
        const float disc = (float)((2 * ROWS + 1) * (2 * ROWS + 1)) - 8.0f * (float)p;
        int i = (int)(((float)(2 * ROWS + 1) - sqrtf(disc)) * 0.5f);
        if (i < 0) i = 0;
        if (i > ROWS - 1) i = ROWS - 1;
        while (i * ROWS - i * (i - 1) / 2 > p) --i;
        while ((i + 1) * ROWS - (i + 1) * i / 2 <= p) ++i;
        const int j = i + (p - (i * ROWS - i * (i - 1) / 2));

        const float* xi = &x[i * T];
        const float* xj = &x[j * T];

        float prod[T];
        #pragma unroll
        for (int t = 0; t < T; ++t) prod[t] = xi[t] * xj[t];

        float cur[NOUT];
        float s = prod[0] + prod[1] + prod[2] + prod[3] + prod[4];
        cur[0] = s * (1.0f / W);
        #pragma unroll
        for (int t = 1; t < NOUT; ++t) {
            s += prod[t + W - 1] - prod[t - 1];
            cur[t] = s * (1.0f / W);
        }

        // 26 floats = 13 float2 stores; base offset p*104 B is 8B-aligned.
        float2* o2 = (float2*)(outb + (size_t)p * NOUT);
        #pragma unroll
        for (int t = 0; t < NOUT / 2; ++t) o2[t] = make_float2(cur[2 * t], cur[2 * t + 1]);
    }
}

extern "C" void kernel_launch(void* const* d_in, const int* in_sizes, int n_in,
                              void* d_out, int out_size, void* d_ws, size_t ws_size,
                              hipStream_t stream) {
    const float* in = (const float*)d_in[0];
    float* out      = (float*)d_out;
    const int B     = in_sizes[0] / (ROWS * T);  // 1024
    ts_cov_kernel<<<B, 256, 0, stream>>>(in, out);
}